// Round 11
// baseline (116.794 us; speedup 1.0000x reference)
//
#include <hip/hip_runtime.h>
#include <math.h>

#define NTOK 9216      // 96*96 tokens
#define CIN  32        // inner channels
#define CC   64        // outer channels
#define NCH1 24        // phase1 n-chunks
#define NT1S 24        // n-tile steps per phase1 chunk: 576/24
#define NCH2 16        // phase2 m-chunks
#define MS2  18        // m-steps (32-wide) per phase2 chunk: 9216/16/32
#define MCH2 576       // m per phase2 chunk
#define LOG2E 1.4426950408889634f
#define C1INIT (-17.312340490667560f)   // -12*log2e
#define C2INIT (-9.3123404906675595f)   // -12*log2e + 8  (+8 = *256 f16-underflow guard)

typedef _Float16 half8 __attribute__((ext_vector_type(8)));
typedef _Float16 half4v __attribute__((ext_vector_type(4)));
typedef float    f32x4 __attribute__((ext_vector_type(4)));

static __device__ __forceinline__ float fexp2(float x) {
#if __has_builtin(__builtin_amdgcn_exp2f)
    return __builtin_amdgcn_exp2f(x);
#else
    return exp2f(x);
#endif
}

// ---------------- conv1: 3x3 s2 p1, LDS-staged, full-oc per block, CIG=8 ----------------
// grid (48, 8): x = output row oh, y = 8-ci group. block 192.
// thread t: oc0 = (t&15)*4, ow0 = (t>>4)*4 -> 4 px x 4 oc accumulators.
__global__ __launch_bounds__(192) void conv3x3_lds96(const float* __restrict__ in,
                                                     const float* __restrict__ w,
                                                     float* __restrict__ outp) {
    __shared__ float li[8][3][100];   // [ci][kh][col] ; col = iw+1 (0..96)
    __shared__ float lw[8][9][64];    // [ci][k][oc]
    const int t = threadIdx.x;
    const int oh = blockIdx.x, grp = blockIdx.y;
    const int ci0 = grp * 8;
    // stage input rows (8ci x 3 x 97), zero-pad iw=-1 and ih=-1
    for (int idx = t; idx < 8 * 3 * 97; idx += 192) {
        int ci = idx / 291, rem = idx % 291;
        int kh = rem / 97, col = rem % 97;
        int ih = 2 * oh - 1 + kh, iw = col - 1;
        float v = 0.f;
        if (ih >= 0 && iw >= 0) v = in[(ci0 + ci) * 9216 + ih * 96 + iw];
        li[ci][kh][col] = v;
    }
    // stage weights (coalesced global order): w[oc*576 + (ci0+ci)*9 + k] -> lw[ci][k][oc]
    for (int idx = t; idx < 8 * 9 * 64; idx += 192) {
        int oc = idx / 72, r = idx % 72;
        int ci = r / 9, k = r % 9;
        lw[ci][k][oc] = w[oc * 576 + (ci0 + ci) * 9 + k];
    }
    __syncthreads();
    const int oc0 = (t & 15) * 4;
    const int ow0 = (t >> 4) * 4;
    float acc[4][4] = {};   // [px][oc]
    #pragma unroll
    for (int ci = 0; ci < 8; ++ci) {
        float wr[9][4];
        #pragma unroll
        for (int k = 0; k < 9; ++k)
            *(float4*)wr[k] = *(const float4*)&lw[ci][k][oc0];
        #pragma unroll
        for (int kh = 0; kh < 3; ++kh) {
            float v[9];
            #pragma unroll
            for (int j = 0; j < 9; ++j) v[j] = li[ci][kh][2 * ow0 + j];
            #pragma unroll
            for (int px = 0; px < 4; ++px)
                #pragma unroll
                for (int kw = 0; kw < 3; ++kw) {
                    float xv = v[2 * px + kw];
                    #pragma unroll
                    for (int o = 0; o < 4; ++o)
                        acc[px][o] = fmaf(xv, wr[kh * 3 + kw][o], acc[px][o]);
                }
        }
    }
    float* op = outp + grp * (CC * 2304) + oh * 48 + ow0;
    #pragma unroll
    for (int o = 0; o < 4; ++o)
        *(float4*)(op + (oc0 + o) * 2304) =
            make_float4(acc[0][o], acc[1][o], acc[2][o], acc[3][o]);
}

// ---------------- generic small conv 3x3 s2 p1: partial over ci-groups ----------------
template<int HIN, int HOUT, int CIG>
__global__ void conv3x3_part(const float* __restrict__ in, const float* __restrict__ w,
                             float* __restrict__ outp) {
    const int p = blockIdx.x * blockDim.x + threadIdx.x;
    if (p >= HOUT * HOUT) return;
    const int oc = blockIdx.y, grp = blockIdx.z;
    const int oh = p / HOUT, ow = p % HOUT;
    const int ci0 = grp * CIG;
    float acc = 0.f;
    #pragma unroll
    for (int ci = 0; ci < CIG; ++ci) {
        const float* ip = in + (ci0 + ci) * HIN * HIN;
        const float* wp = w + oc * CC * 9 + (ci0 + ci) * 9;
        #pragma unroll
        for (int kh = 0; kh < 3; ++kh) {
            int ih = oh * 2 - 1 + kh;
            bool okh = (unsigned)ih < (unsigned)HIN;
            #pragma unroll
            for (int kw = 0; kw < 3; ++kw) {
                int iw = ow * 2 - 1 + kw;
                float v = (okh && (unsigned)iw < (unsigned)HIN) ? ip[ih * HIN + iw] : 0.f;
                acc = fmaf(v, wp[kh * 3 + kw], acc);
            }
        }
    }
    outp[grp * (CC * HOUT * HOUT) + oc * HOUT * HOUT + p] = acc;
}

// ---------------- merge conv partials + bias + (leaky)relu, float4 ----------------
template<int NG, int HW, int LRELU>
__global__ void conv_merge4(const float* __restrict__ parts, const float* __restrict__ b,
                            float* __restrict__ out) {
    int i4 = blockIdx.x * 256 + threadIdx.x;    // CC*HW/4 total
    int oc = (i4 * 4) / HW;
    float bb = b[oc];
    float4 acc = make_float4(bb, bb, bb, bb);
    #pragma unroll
    for (int g = 0; g < NG; ++g) {
        float4 p = *(const float4*)(parts + g * (CC * HW) + i4 * 4);
        acc.x += p.x; acc.y += p.y; acc.z += p.z; acc.w += p.w;
    }
    if (LRELU) {
        acc.x = acc.x >= 0.f ? acc.x : 0.2f * acc.x;
        acc.y = acc.y >= 0.f ? acc.y : 0.2f * acc.y;
        acc.z = acc.z >= 0.f ? acc.z : 0.2f * acc.z;
        acc.w = acc.w >= 0.f ? acc.w : 0.2f * acc.w;
    }
    *(float4*)(out + i4 * 4) = acc;
}

// ---------------- gate helper: bilinear 12->96 + sigmoid ----------------
static __device__ __forceinline__ float gate_val(const float* y3c, int n) {
    int h = n / 96, wc = n % 96;
    float fh = (h + 0.5f) * 0.125f - 0.5f;
    float fw = (wc + 0.5f) * 0.125f - 0.5f;
    int h0 = (int)floorf(fh); float ah = fh - (float)h0;
    int w0 = (int)floorf(fw); float aw = fw - (float)w0;
    int h0c = min(max(h0, 0), 11), h1c = min(max(h0 + 1, 0), 11);
    int w0c = min(max(w0, 0), 11), w1c = min(max(w0 + 1, 0), 11);
    float v = (1.f - ah) * ((1.f - aw) * y3c[h0c * 12 + w0c] + aw * y3c[h0c * 12 + w1c])
            +         ah * ((1.f - aw) * y3c[h1c * 12 + w0c] + aw * y3c[h1c * 12 + w1c]);
    return 1.f / (1.f + __expf(-v));
}

// ---------------- fused: merge conv3 partials + gate -> xg ----------------
__global__ void gate_fused(const float* __restrict__ x, const float* __restrict__ cp3,
                           const float* __restrict__ d3b, float* __restrict__ xg) {
    __shared__ float y3c[144];
    const int b = blockIdx.x, t = threadIdx.x;
    const int c = b / 36;
    if (t < 144) {
        float acc = d3b[c];
        #pragma unroll
        for (int g = 0; g < 16; ++g)
            acc += cp3[g * (CC * 144) + c * 144 + t];
        y3c[t] = acc;
    }
    __syncthreads();
    int idx = b * 256 + t;
    int n = idx % 9216;
    float sg = gate_val(y3c, n);
    xg[idx] = sg * x[idx];
}

// ---------------- 1x1 convs -> f16 fragments, LDS-staged xg tile ----------------
// grid (144, 4), block 256. Block = 64 tokens x 8-ci group; thread = (nl, 2 ci).
__global__ __launch_bounds__(256) void conv1x1_frag(
    const float* __restrict__ xg,
    const float* __restrict__ gw, const float* __restrict__ gb,
    const float* __restrict__ thw, const float* __restrict__ thb,
    const float* __restrict__ phw, const float* __restrict__ phb,
    _Float16* __restrict__ txF, _Float16* __restrict__ pxF,
    _Float16* __restrict__ gxF) {
    __shared__ float xgl[64][64];   // 16 KB
    const int t = threadIdx.x;
    const int n0 = blockIdx.x * 64;
    for (int idx = t; idx < 64 * 64; idx += 256) {
        int c = idx >> 6, nl = idx & 63;
        xgl[c][nl] = xg[c * NTOK + n0 + nl];
    }
    __syncthreads();
    const int nl = t & 63, sub = t >> 6;
    const int n = n0 + nl;
    const int ci0 = blockIdx.y * 8 + sub * 2;
    float ag[2], at[2], ap[2];
    #pragma unroll
    for (int j = 0; j < 2; ++j) {
        ag[j] = gb[ci0 + j]; at[j] = thb[ci0 + j]; ap[j] = phb[ci0 + j];
    }
    #pragma unroll 8
    for (int c = 0; c < CC; ++c) {
        float v = xgl[c][nl];
        #pragma unroll
        for (int j = 0; j < 2; ++j) {
            ag[j] = fmaf(gw[(ci0 + j) * CC + c],  v, ag[j]);
            at[j] = fmaf(thw[(ci0 + j) * CC + c], v, at[j]);
            ap[j] = fmaf(phw[(ci0 + j) * CC + c], v, ap[j]);
        }
    }
    #pragma unroll
    for (int j = 0; j < 2; ++j) {
        int ci = ci0 + j;
        int addr_ab = (n >> 4) * 512 + (((n & 15) | (((ci & 15) >> 2) << 4)) * 8)
                    + (((ci >> 4) << 2) | (ci & 3));
        txF[addr_ab] = (_Float16)(at[j] * LOG2E);
        pxF[addr_ab] = (_Float16)ap[j];
        int addr_g = ((n >> 5) * 2 + (ci >> 4)) * 512
                   + (((ci & 15) | (((n & 15) >> 2) << 4)) * 8)
                   + ((((n >> 4) & 1) << 2) | (n & 3));
        gxF[addr_g] = (_Float16)ag[j];
    }
}

// ---------------- phase 1: Dp[m] = sum_n exp2(s'), tf staged in LDS ----------------
__global__ __launch_bounds__(256) void phase1(const _Float16* __restrict__ txF,
                                              const _Float16* __restrict__ pxF,
                                              float* __restrict__ Dp) {
    __shared__ _Float16 tls[4][512];   // 4 KB
    const int t = threadIdx.x;
    int w = t >> 6, l = t & 63;
    int mtile0 = (blockIdx.x * 4 + w) * 4;
    half8 pf[4];
    #pragma unroll
    for (int j = 0; j < 4; ++j)
        pf[j] = *(const half8*)(pxF + (mtile0 + j) * 512 + l * 8);
    f32x4 cini = {C1INIT, C1INIT, C1INIT, C1INIT};
    float dsum[4][4] = {};
    int nt0 = blockIdx.y * NT1S;
    const int ltile = t >> 6, loff = (t & 63) * 8;
    for (int g = 0; g < NT1S / 4; ++g) {
        __syncthreads();
        *(half8*)(&tls[0][0] + t * 8) =
            *(const half8*)(txF + (nt0 + g * 4 + ltile) * 512 + loff);
        __syncthreads();
        #pragma unroll
        for (int i = 0; i < 4; ++i) {
            half8 tf = *(const half8*)(&tls[i][l * 8]);
            #pragma unroll
            for (int j = 0; j < 4; ++j) {
                f32x4 s = __builtin_amdgcn_mfma_f32_16x16x32_f16(pf[j], tf, cini, 0, 0, 0);
                #pragma unroll
                for (int r = 0; r < 4; ++r)
                    dsum[j][r] += fexp2(s[r]);
            }
        }
    }
    #pragma unroll
    for (int off = 1; off < 16; off <<= 1)
        #pragma unroll
        for (int j = 0; j < 4; ++j)
            #pragma unroll
            for (int r = 0; r < 4; ++r)
                dsum[j][r] += __shfl_xor(dsum[j][r], off);
    if ((l & 15) == 0) {
        #pragma unroll
        for (int j = 0; j < 4; ++j) {
            int m = (mtile0 + j) * 16 + (l >> 4) * 4;
            #pragma unroll
            for (int r = 0; r < 4; ++r)
                Dp[blockIdx.y * NTOK + m + r] = dsum[j][r];
        }
    }
}

// ---------------- phase 2: y2 = sum_m 2^(s'-log2D)*g; pf/gf staged in LDS; f16 out ----------------
__global__ __launch_bounds__(256) void phase2(const _Float16* __restrict__ txF,
                                              const _Float16* __restrict__ pxF,
                                              const _Float16* __restrict__ gxF,
                                              const float* __restrict__ Dp,
                                              _Float16* __restrict__ y2p) {
    __shared__ float l2D[MCH2];        // 2.3 KB
    __shared__ _Float16 pg[8][512];    // 8 KB: tiles 0-3 = pxF, 4-7 = gxF
    const int t = threadIdx.x;
    int mbase = blockIdx.y * MCH2;
    for (int i = t; i < MCH2; i += 256) {
        float D = 0.f;
        #pragma unroll
        for (int ch = 0; ch < NCH1; ++ch) D += Dp[ch * NTOK + mbase + i];
        l2D[i] = __log2f(D);
    }
    int w = t >> 6, l = t & 63;
    int ntile0 = (blockIdx.x * 4 + w) * 4;
    half8 tf[4];
    #pragma unroll
    for (int j = 0; j < 4; ++j)
        tf[j] = *(const half8*)(txF + (ntile0 + j) * 512 + l * 8);
    int khi = (l >> 4) * 4;
    f32x4 zero = {0.f, 0.f, 0.f, 0.f};
    f32x4 c2v = {C2INIT, C2INIT, C2INIT, C2INIT};
    f32x4 acc[4][2];
    #pragma unroll
    for (int j = 0; j < 4; ++j) { acc[j][0] = zero; acc[j][1] = zero; }
    for (int g = 0; g < MS2 / 2; ++g) {
        int pb = (mbase + g * 64) >> 4;   // 4 consecutive 16-tiles; same index for gxF
        __syncthreads();
        #pragma unroll
        for (int uu = 0; uu < 2; ++uu) {
            int u = t + uu * 256;
            int tile = u >> 6, off = (u & 63) * 8;
            const _Float16* s = (tile < 4) ? (pxF + (pb + tile) * 512 + off)
                                           : (gxF + (pb + tile - 4) * 512 + off);
            *(half8*)(&pg[0][0] + u * 8) = *(const half8*)s;
        }
        __syncthreads();
        #pragma unroll
        for (int s2 = 0; s2 < 2; ++s2) {
            int mloc = g * 64 + s2 * 32;
            half8 pf0 = *(const half8*)(&pg[2 * s2][l * 8]);
            half8 pf1 = *(const half8*)(&pg[2 * s2 + 1][l * 8]);
            half8 gf0 = *(const half8*)(&pg[4 + 2 * s2][l * 8]);
            half8 gf1 = *(const half8*)(&pg[5 + 2 * s2][l * 8]);
            f32x4 l2a = *(const f32x4*)&l2D[mloc + khi];
            f32x4 l2b = *(const f32x4*)&l2D[mloc + 16 + khi];
            f32x4 cini0 = c2v - l2a;
            f32x4 cini1 = c2v - l2b;
            #pragma unroll
            for (int j = 0; j < 4; ++j) {
                f32x4 s0 = __builtin_amdgcn_mfma_f32_16x16x32_f16(pf0, tf[j], cini0, 0, 0, 0);
                f32x4 s1 = __builtin_amdgcn_mfma_f32_16x16x32_f16(pf1, tf[j], cini1, 0, 0, 0);
                half8 ff;
                #pragma unroll
                for (int r = 0; r < 4; ++r) {
                    ff[r]     = (_Float16)fexp2(s0[r]);
                    ff[4 + r] = (_Float16)fexp2(s1[r]);
                }
                acc[j][0] = __builtin_amdgcn_mfma_f32_16x16x32_f16(ff, gf0, acc[j][0], 0, 0, 0);
                acc[j][1] = __builtin_amdgcn_mfma_f32_16x16x32_f16(ff, gf1, acc[j][1], 0, 0, 0);
            }
        }
    }
    _Float16* base = y2p + blockIdx.y * (CIN * NTOK);
    #pragma unroll
    for (int j = 0; j < 4; ++j) {
        int n = (ntile0 + j) * 16 + khi;
        half4v v0, v1;
        #pragma unroll
        for (int r = 0; r < 4; ++r) {
            v0[r] = (_Float16)(acc[j][0][r] * 0.00390625f);
            v1[r] = (_Float16)(acc[j][1][r] * 0.00390625f);
        }
        *(half4v*)(base + (l & 15) * NTOK + n)        = v0;
        *(half4v*)(base + (16 + (l & 15)) * NTOK + n) = v1;
    }
}

// ---------------- merge y2 partials (f16 in, f32 out) ----------------
__global__ void mergeY2(const _Float16* __restrict__ y2p, float* __restrict__ att) {
    int i4 = blockIdx.x * 256 + threadIdx.x;   // 32*9216/4 = 73728 -> 288 blocks
    float4 s = make_float4(0.f, 0.f, 0.f, 0.f);
    #pragma unroll
    for (int ch = 0; ch < NCH2; ++ch) {
        half4v p = *(const half4v*)(y2p + ch * (CIN * NTOK) + i4 * 4);
        s.x += (float)p[0]; s.y += (float)p[1]; s.z += (float)p[2]; s.w += (float)p[3];
    }
    *(float4*)(att + i4 * 4) = s;
}

// ---------------- final 1x1 conv + residual ----------------
__global__ void final_conv(const float* __restrict__ att, const float* __restrict__ Ww,
                           const float* __restrict__ Wb, const float* __restrict__ xg,
                           float* __restrict__ out) {
    int co = blockIdx.y;
    int n = blockIdx.x * 256 + threadIdx.x;
    float acc = Wb[co];
    #pragma unroll
    for (int ci = 0; ci < CIN; ++ci)
        acc = fmaf(Ww[co * CIN + ci], att[ci * NTOK + n], acc);
    out[co * NTOK + n] = acc + xg[co * NTOK + n];
}

extern "C" void kernel_launch(void* const* d_in, const int* in_sizes, int n_in,
                              void* d_out, int out_size, void* d_ws, size_t ws_size,
                              hipStream_t stream) {
    const float* x   = (const float*)d_in[0];
    const float* d1w = (const float*)d_in[1];  const float* d1b = (const float*)d_in[2];
    const float* d2w = (const float*)d_in[3];  const float* d2b = (const float*)d_in[4];
    const float* d3w = (const float*)d_in[5];  const float* d3b = (const float*)d_in[6];
    const float* gw  = (const float*)d_in[7];  const float* gb  = (const float*)d_in[8];
    const float* thw = (const float*)d_in[9];  const float* thb = (const float*)d_in[10];
    const float* phw = (const float*)d_in[11]; const float* phb = (const float*)d_in[12];
    const float* Ww  = (const float*)d_in[13]; const float* Wb  = (const float*)d_in[14];
    float* out = (float*)d_out;

    float* W    = (float*)d_ws;
    float* xg   = W;                  // 589824
    float* y1   = W + 589824;         // -> 737280
    float* y2c  = W + 737280;         // -> 774144
    float* Dp   = W + 774144;         // 24*9216 -> 995328
    float* att  = W + 995328;         // -> 1290240
    float* cp1  = W + 1290240;        // 8*147456 = 1179648 -> 2469888
    float* cp2  = W + 2469888;        // 16*36864 = 589824  -> 3059712
    float* cp3  = W + 3059712;        // 16*9216  = 147456  -> 3207168
    _Float16* txF  = (_Float16*)(W + 3207168);  // 294912 f16 = 147456 fl
    _Float16* pxF  = (_Float16*)(W + 3354624);
    _Float16* gxF  = (_Float16*)(W + 3502080);  // -> 3649536
    _Float16* y2pH = (_Float16*)(W + 3649536);  // 16*294912 f16 -> 4829184 fl = 19.3 MB

    // gating branch (reads ORIGINAL x)
    conv3x3_lds96<<<dim3(48, 8), 192, 0, stream>>>(x, d1w, cp1);
    conv_merge4<8, 2304, 1><<<144, 256, 0, stream>>>(cp1, d1b, y1);
    conv3x3_part<48, 24, 4><<<dim3(3, CC, 16), 192, 0, stream>>>(y1, d2w, cp2);
    conv_merge4<16, 576, 1><<<36, 256, 0, stream>>>(cp2, d2b, y2c);
    conv3x3_part<24, 12, 4><<<dim3(1, CC, 16), 192, 0, stream>>>(y2c, d3w, cp3);
    gate_fused<<<2304, 256, 0, stream>>>(x, cp3, d3b, xg);

    // 1x1 projections -> f16 fragments direct (LDS-tiled xg)
    conv1x1_frag<<<dim3(144, 4), 256, 0, stream>>>(xg, gw, gb, thw, thb, phw, phb,
                                                   txF, pxF, gxF);

    // attention via MFMA (operands LDS-shared across waves)
    phase1<<<dim3(36, NCH1), 256, 0, stream>>>(txF, pxF, Dp);
    phase2<<<dim3(36, NCH2), 256, 0, stream>>>(txF, pxF, gxF, Dp, y2pH);
    mergeY2<<<288, 256, 0, stream>>>(y2pH, att);

    // output
    final_conv<<<dim3(36, CC), 256, 0, stream>>>(att, Ww, Wb, xg, out);
}

// Round 12
// 107.528 us; speedup vs baseline: 1.0862x; 1.0862x over previous
//
#include <hip/hip_runtime.h>
#include <math.h>

#define NTOK 9216      // 96*96 tokens
#define CIN  32        // inner channels
#define CC   64        // outer channels
#define NCH1 24        // phase1 n-chunks
#define NT1S 24        // n-tile steps per phase1 chunk: 576/24
#define NCH2 16        // phase2 m-chunks
#define MS2  18        // m-steps (32-wide) per phase2 chunk: 9216/16/32
#define MCH2 576       // m per phase2 chunk
#define LOG2E 1.4426950408889634f
#define C1INIT (-17.312340490667560f)   // -12*log2e
#define C2INIT (-9.3123404906675595f)   // -12*log2e + 8  (+8 = *256 f16-underflow guard)

typedef _Float16 half8 __attribute__((ext_vector_type(8)));
typedef _Float16 half4v __attribute__((ext_vector_type(4)));
typedef float    f32x4 __attribute__((ext_vector_type(4)));

static __device__ __forceinline__ float fexp2(float x) {
#if __has_builtin(__builtin_amdgcn_exp2f)
    return __builtin_amdgcn_exp2f(x);
#else
    return exp2f(x);
#endif
}

// ---------------- conv1: 3x3 s2 p1, LDS-staged, full-oc per block, f16 partials ----------------
// grid (48, 16): x = output row oh, y = 4-ci group. block 192.
__global__ __launch_bounds__(192) void conv3x3_lds96(const float* __restrict__ in,
                                                     const float* __restrict__ w,
                                                     _Float16* __restrict__ outp) {
    __shared__ float li[4][3][100];   // [ci][kh][col] ; col = iw+1
    __shared__ float lw[4][9][64];    // [ci][k][oc]
    const int t = threadIdx.x;
    const int oh = blockIdx.x, grp = blockIdx.y;
    const int ci0 = grp * 4;
    for (int idx = t; idx < 4 * 3 * 97; idx += 192) {
        int ci = idx / 291, rem = idx % 291;
        int kh = rem / 97, col = rem % 97;
        int ih = 2 * oh - 1 + kh, iw = col - 1;
        float v = 0.f;
        if (ih >= 0 && iw >= 0) v = in[(ci0 + ci) * 9216 + ih * 96 + iw];
        li[ci][kh][col] = v;
    }
    for (int idx = t; idx < 4 * 9 * 64; idx += 192) {
        int oc = idx / 36, r = idx % 36;
        int ci = r / 9, k = r % 9;
        lw[ci][k][oc] = w[oc * 576 + (ci0 + ci) * 9 + k];
    }
    __syncthreads();
    const int oc0 = (t & 15) * 4;
    const int ow0 = (t >> 4) * 4;
    float acc[4][4] = {};   // [px][oc]
    #pragma unroll
    for (int ci = 0; ci < 4; ++ci) {
        float wr[9][4];
        #pragma unroll
        for (int k = 0; k < 9; ++k)
            *(float4*)wr[k] = *(const float4*)&lw[ci][k][oc0];
        #pragma unroll
        for (int kh = 0; kh < 3; ++kh) {
            float v[9];
            #pragma unroll
            for (int j = 0; j < 9; ++j) v[j] = li[ci][kh][2 * ow0 + j];
            #pragma unroll
            for (int px = 0; px < 4; ++px)
                #pragma unroll
                for (int kw = 0; kw < 3; ++kw) {
                    float xv = v[2 * px + kw];
                    #pragma unroll
                    for (int o = 0; o < 4; ++o)
                        acc[px][o] = fmaf(xv, wr[kh * 3 + kw][o], acc[px][o]);
                }
        }
    }
    _Float16* op = outp + grp * (CC * 2304) + oh * 48 + ow0;
    #pragma unroll
    for (int o = 0; o < 4; ++o) {
        half4v vv = {(_Float16)acc[0][o], (_Float16)acc[1][o],
                     (_Float16)acc[2][o], (_Float16)acc[3][o]};
        *(half4v*)(op + (oc0 + o) * 2304) = vv;
    }
}

// ---------------- generic small conv 3x3 s2 p1 (f16 in/out): partial over ci-groups ----------------
template<int HIN, int HOUT, int CIG>
__global__ void conv3x3_part(const _Float16* __restrict__ in, const float* __restrict__ w,
                             _Float16* __restrict__ outp) {
    const int p = blockIdx.x * blockDim.x + threadIdx.x;
    if (p >= HOUT * HOUT) return;
    const int oc = blockIdx.y, grp = blockIdx.z;
    const int oh = p / HOUT, ow = p % HOUT;
    const int ci0 = grp * CIG;
    float acc = 0.f;
    #pragma unroll
    for (int ci = 0; ci < CIG; ++ci) {
        const _Float16* ip = in + (ci0 + ci) * HIN * HIN;
        const float* wp = w + oc * CC * 9 + (ci0 + ci) * 9;
        #pragma unroll
        for (int kh = 0; kh < 3; ++kh) {
            int ih = oh * 2 - 1 + kh;
            bool okh = (unsigned)ih < (unsigned)HIN;
            #pragma unroll
            for (int kw = 0; kw < 3; ++kw) {
                int iw = ow * 2 - 1 + kw;
                float v = (okh && (unsigned)iw < (unsigned)HIN) ? (float)ip[ih * HIN + iw] : 0.f;
                acc = fmaf(v, wp[kh * 3 + kw], acc);
            }
        }
    }
    outp[grp * (CC * HOUT * HOUT) + oc * HOUT * HOUT + p] = (_Float16)acc;
}

// ---------------- merge conv partials (f16) + bias + (leaky)relu -> f16 ----------------
template<int NG, int HW, int LRELU>
__global__ void conv_merge4h(const _Float16* __restrict__ parts, const float* __restrict__ b,
                             _Float16* __restrict__ out) {
    int i4 = blockIdx.x * 256 + threadIdx.x;    // CC*HW/4 total
    int oc = (i4 * 4) / HW;
    float bb = b[oc];
    float4 acc = make_float4(bb, bb, bb, bb);
    #pragma unroll
    for (int g = 0; g < NG; ++g) {
        half4v p = *(const half4v*)(parts + g * (CC * HW) + i4 * 4);
        acc.x += (float)p[0]; acc.y += (float)p[1];
        acc.z += (float)p[2]; acc.w += (float)p[3];
    }
    if (LRELU) {
        acc.x = acc.x >= 0.f ? acc.x : 0.2f * acc.x;
        acc.y = acc.y >= 0.f ? acc.y : 0.2f * acc.y;
        acc.z = acc.z >= 0.f ? acc.z : 0.2f * acc.z;
        acc.w = acc.w >= 0.f ? acc.w : 0.2f * acc.w;
    }
    half4v vo = {(_Float16)acc.x, (_Float16)acc.y, (_Float16)acc.z, (_Float16)acc.w};
    *(half4v*)(out + i4 * 4) = vo;
}

// ---------------- gate helper: bilinear 12->96 + sigmoid ----------------
static __device__ __forceinline__ float gate_val(const float* y3c, int n) {
    int h = n / 96, wc = n % 96;
    float fh = (h + 0.5f) * 0.125f - 0.5f;
    float fw = (wc + 0.5f) * 0.125f - 0.5f;
    int h0 = (int)floorf(fh); float ah = fh - (float)h0;
    int w0 = (int)floorf(fw); float aw = fw - (float)w0;
    int h0c = min(max(h0, 0), 11), h1c = min(max(h0 + 1, 0), 11);
    int w0c = min(max(w0, 0), 11), w1c = min(max(w0 + 1, 0), 11);
    float v = (1.f - ah) * ((1.f - aw) * y3c[h0c * 12 + w0c] + aw * y3c[h0c * 12 + w1c])
            +         ah * ((1.f - aw) * y3c[h1c * 12 + w0c] + aw * y3c[h1c * 12 + w1c]);
    return 1.f / (1.f + __expf(-v));
}

// ---------------- fused: merge conv3 partials (f16) + gate -> xg (f16) ----------------
__global__ void gate_fused(const float* __restrict__ x, const _Float16* __restrict__ cp3,
                           const float* __restrict__ d3b, _Float16* __restrict__ xg) {
    __shared__ float y3c[144];
    const int b = blockIdx.x, t = threadIdx.x;
    const int c = b / 36;
    if (t < 144) {
        float acc = d3b[c];
        #pragma unroll
        for (int g = 0; g < 16; ++g)
            acc += (float)cp3[g * (CC * 144) + c * 144 + t];
        y3c[t] = acc;
    }
    __syncthreads();
    int idx = b * 256 + t;
    int n = idx % 9216;
    float sg = gate_val(y3c, n);
    xg[idx] = (_Float16)(sg * x[idx]);
}

// ---------------- 1x1 convs (xg f16) -> f16 fragments written DIRECTLY ----------------
__global__ void conv1x1_frag(const _Float16* __restrict__ xg,
                             const float* __restrict__ gw, const float* __restrict__ gb,
                             const float* __restrict__ thw, const float* __restrict__ thb,
                             const float* __restrict__ phw, const float* __restrict__ phb,
                             _Float16* __restrict__ txF, _Float16* __restrict__ pxF,
                             _Float16* __restrict__ gxF) {
    int ci = blockIdx.y;
    int n = blockIdx.x * 256 + threadIdx.x;
    float ag = gb[ci], at = thb[ci], ap = phb[ci];
    #pragma unroll 8
    for (int c = 0; c < CC; ++c) {
        float v = (float)xg[c * NTOK + n];
        ag = fmaf(gw[ci * CC + c],  v, ag);
        at = fmaf(thw[ci * CC + c], v, at);
        ap = fmaf(phw[ci * CC + c], v, ap);
    }
    int addr_ab = (n >> 4) * 512 + (((n & 15) | (((ci & 15) >> 2) << 4)) * 8)
                + (((ci >> 4) << 2) | (ci & 3));
    txF[addr_ab] = (_Float16)(at * LOG2E);
    pxF[addr_ab] = (_Float16)ap;
    int addr_g = ((n >> 5) * 2 + (ci >> 4)) * 512
               + (((ci & 15) | (((n & 15) >> 2) << 4)) * 8)
               + ((((n >> 4) & 1) << 2) | (n & 3));
    gxF[addr_g] = (_Float16)ag;
}

// ---------------- phase 1: Dp[m] = sum_n exp2(s'), 4 m-tiles per wave ----------------
__global__ __launch_bounds__(256) void phase1(const _Float16* __restrict__ txF,
                                              const _Float16* __restrict__ pxF,
                                              float* __restrict__ Dp) {
    int w = threadIdx.x >> 6, l = threadIdx.x & 63;
    int mtile0 = (blockIdx.x * 4 + w) * 4;
    half8 pf[4];
    #pragma unroll
    for (int j = 0; j < 4; ++j)
        pf[j] = *(const half8*)(pxF + (mtile0 + j) * 512 + l * 8);
    f32x4 cini = {C1INIT, C1INIT, C1INIT, C1INIT};
    float dsum[4][4] = {};
    int nt0 = blockIdx.y * NT1S;
    #pragma unroll 2
    for (int i = 0; i < NT1S; ++i) {
        half8 tf = *(const half8*)(txF + (nt0 + i) * 512 + l * 8);
        #pragma unroll
        for (int j = 0; j < 4; ++j) {
            f32x4 s = __builtin_amdgcn_mfma_f32_16x16x32_f16(pf[j], tf, cini, 0, 0, 0);
            #pragma unroll
            for (int r = 0; r < 4; ++r)
                dsum[j][r] += fexp2(s[r]);
        }
    }
    #pragma unroll
    for (int off = 1; off < 16; off <<= 1)
        #pragma unroll
        for (int j = 0; j < 4; ++j)
            #pragma unroll
            for (int r = 0; r < 4; ++r)
                dsum[j][r] += __shfl_xor(dsum[j][r], off);
    if ((l & 15) == 0) {
        #pragma unroll
        for (int j = 0; j < 4; ++j) {
            int m = (mtile0 + j) * 16 + (l >> 4) * 4;
            #pragma unroll
            for (int r = 0; r < 4; ++r)
                Dp[blockIdx.y * NTOK + m + r] = dsum[j][r];
        }
    }
}

// ---------------- phase 2: y2 = sum_m 2^(s'-log2D)*g; Dp merged in prologue; f16 out ----------------
__global__ __launch_bounds__(256) void phase2(const _Float16* __restrict__ txF,
                                              const _Float16* __restrict__ pxF,
                                              const _Float16* __restrict__ gxF,
                                              const float* __restrict__ Dp,
                                              _Float16* __restrict__ y2p) {
    __shared__ float l2D[MCH2];
    int mbase = blockIdx.y * MCH2;
    for (int i = threadIdx.x; i < MCH2; i += 256) {
        float D = 0.f;
        #pragma unroll
        for (int ch = 0; ch < NCH1; ++ch) D += Dp[ch * NTOK + mbase + i];
        l2D[i] = __log2f(D);
    }
    __syncthreads();
    int w = threadIdx.x >> 6, l = threadIdx.x & 63;
    int ntile0 = (blockIdx.x * 4 + w) * 4;
    half8 tf[4];
    #pragma unroll
    for (int j = 0; j < 4; ++j)
        tf[j] = *(const half8*)(txF + (ntile0 + j) * 512 + l * 8);
    int khi = (l >> 4) * 4;
    f32x4 zero = {0.f, 0.f, 0.f, 0.f};
    f32x4 c2v = {C2INIT, C2INIT, C2INIT, C2INIT};
    f32x4 acc[4][2];
    #pragma unroll
    for (int j = 0; j < 4; ++j) { acc[j][0] = zero; acc[j][1] = zero; }
    #pragma unroll 2
    for (int ms = 0; ms < MS2; ++ms) {
        int m0 = mbase + ms * 32;
        int mloc = ms * 32;
        int mt16 = m0 >> 4;
        half8 pf0 = *(const half8*)(pxF + mt16 * 512 + l * 8);
        half8 pf1 = *(const half8*)(pxF + (mt16 + 1) * 512 + l * 8);
        f32x4 l2a = *(const f32x4*)&l2D[mloc + khi];
        f32x4 l2b = *(const f32x4*)&l2D[mloc + 16 + khi];
        f32x4 cini0 = c2v - l2a;
        f32x4 cini1 = c2v - l2b;
        int gt = (m0 >> 5) * 2;
        half8 gf0 = *(const half8*)(gxF + gt * 512 + l * 8);
        half8 gf1 = *(const half8*)(gxF + (gt + 1) * 512 + l * 8);
        #pragma unroll
        for (int j = 0; j < 4; ++j) {
            f32x4 s0 = __builtin_amdgcn_mfma_f32_16x16x32_f16(pf0, tf[j], cini0, 0, 0, 0);
            f32x4 s1 = __builtin_amdgcn_mfma_f32_16x16x32_f16(pf1, tf[j], cini1, 0, 0, 0);
            half8 ff;
            #pragma unroll
            for (int r = 0; r < 4; ++r) {
                ff[r]     = (_Float16)fexp2(s0[r]);
                ff[4 + r] = (_Float16)fexp2(s1[r]);
            }
            acc[j][0] = __builtin_amdgcn_mfma_f32_16x16x32_f16(ff, gf0, acc[j][0], 0, 0, 0);
            acc[j][1] = __builtin_amdgcn_mfma_f32_16x16x32_f16(ff, gf1, acc[j][1], 0, 0, 0);
        }
    }
    _Float16* base = y2p + blockIdx.y * (CIN * NTOK);
    #pragma unroll
    for (int j = 0; j < 4; ++j) {
        int n = (ntile0 + j) * 16 + khi;
        half4v v0, v1;
        #pragma unroll
        for (int r = 0; r < 4; ++r) {
            v0[r] = (_Float16)(acc[j][0][r] * 0.00390625f);
            v1[r] = (_Float16)(acc[j][1][r] * 0.00390625f);
        }
        *(half4v*)(base + (l & 15) * NTOK + n)        = v0;
        *(half4v*)(base + (16 + (l & 15)) * NTOK + n) = v1;
    }
}

// ---------------- merge y2 partials (f16 in, f16 out) ----------------
__global__ void mergeY2(const _Float16* __restrict__ y2p, _Float16* __restrict__ att) {
    int i4 = blockIdx.x * 256 + threadIdx.x;   // 32*9216/4 = 73728 -> 288 blocks
    float4 s = make_float4(0.f, 0.f, 0.f, 0.f);
    #pragma unroll
    for (int ch = 0; ch < NCH2; ++ch) {
        half4v p = *(const half4v*)(y2p + ch * (CIN * NTOK) + i4 * 4);
        s.x += (float)p[0]; s.y += (float)p[1]; s.z += (float)p[2]; s.w += (float)p[3];
    }
    half4v vo = {(_Float16)s.x, (_Float16)s.y, (_Float16)s.z, (_Float16)s.w};
    *(half4v*)(att + i4 * 4) = vo;
}

// ---------------- final 1x1 conv + residual (att/xg f16, out f32) ----------------
__global__ void final_conv(const _Float16* __restrict__ att, const float* __restrict__ Ww,
                           const float* __restrict__ Wb, const _Float16* __restrict__ xg,
                           float* __restrict__ out) {
    int co = blockIdx.y;
    int n = blockIdx.x * 256 + threadIdx.x;
    float acc = Wb[co];
    #pragma unroll
    for (int ci = 0; ci < CIN; ++ci)
        acc = fmaf(Ww[co * CIN + ci], (float)att[ci * NTOK + n], acc);
    out[co * NTOK + n] = acc + (float)xg[co * NTOK + n];
}

extern "C" void kernel_launch(void* const* d_in, const int* in_sizes, int n_in,
                              void* d_out, int out_size, void* d_ws, size_t ws_size,
                              hipStream_t stream) {
    const float* x   = (const float*)d_in[0];
    const float* d1w = (const float*)d_in[1];  const float* d1b = (const float*)d_in[2];
    const float* d2w = (const float*)d_in[3];  const float* d2b = (const float*)d_in[4];
    const float* d3w = (const float*)d_in[5];  const float* d3b = (const float*)d_in[6];
    const float* gw  = (const float*)d_in[7];  const float* gb  = (const float*)d_in[8];
    const float* thw = (const float*)d_in[9];  const float* thb = (const float*)d_in[10];
    const float* phw = (const float*)d_in[11]; const float* phb = (const float*)d_in[12];
    const float* Ww  = (const float*)d_in[13]; const float* Wb  = (const float*)d_in[14];
    float* out = (float*)d_out;

    float* W = (float*)d_ws;
    _Float16* xg   = (_Float16*)(W);            // 589824 f16 = 294912 fl
    _Float16* y1   = (_Float16*)(W + 294912);   // 147456 f16 = 73728 fl -> 368640
    _Float16* y2c  = (_Float16*)(W + 368640);   // 36864 f16 = 18432 fl -> 387072
    float*    Dp   = W + 387072;                // 24*9216 f32 = 221184 fl -> 608256
    _Float16* att  = (_Float16*)(W + 608256);   // 294912 f16 = 147456 fl -> 755712
    _Float16* cp1  = (_Float16*)(W + 755712);   // 16*147456 f16 = 1179648 fl -> 1935360
    _Float16* cp2  = (_Float16*)(W + 1935360);  // 16*36864 f16 = 294912 fl -> 2230272
    _Float16* cp3  = (_Float16*)(W + 2230272);  // 16*9216 f16 = 73728 fl -> 2304000
    _Float16* txF  = (_Float16*)(W + 2304000);  // 294912 f16 -> 2451456
    _Float16* pxF  = (_Float16*)(W + 2451456);  // -> 2598912
    _Float16* gxF  = (_Float16*)(W + 2598912);  // -> 2746368
    _Float16* y2pH = (_Float16*)(W + 2746368);  // 16*294912 f16 -> 5105664 fl = 20.4 MB

    // gating branch (reads ORIGINAL x)
    conv3x3_lds96<<<dim3(48, 16), 192, 0, stream>>>(x, d1w, cp1);
    conv_merge4h<16, 2304, 1><<<144, 256, 0, stream>>>(cp1, d1b, y1);
    conv3x3_part<48, 24, 4><<<dim3(3, CC, 16), 192, 0, stream>>>(y1, d2w, cp2);
    conv_merge4h<16, 576, 1><<<36, 256, 0, stream>>>(cp2, d2b, y2c);
    conv3x3_part<24, 12, 4><<<dim3(1, CC, 16), 192, 0, stream>>>(y2c, d3w, cp3);
    gate_fused<<<2304, 256, 0, stream>>>(x, cp3, d3b, xg);

    // 1x1 projections -> f16 fragments direct
    conv1x1_frag<<<dim3(36, CIN), 256, 0, stream>>>(xg, gw, gb, thw, thb, phw, phb,
                                                    txF, pxF, gxF);

    // attention via MFMA
    phase1<<<dim3(36, NCH1), 256, 0, stream>>>(txF, pxF, Dp);
    phase2<<<dim3(36, NCH2), 256, 0, stream>>>(txF, pxF, gxF, Dp, y2pH);
    mergeY2<<<288, 256, 0, stream>>>(y2pH, att);

    // output
    final_conv<<<dim3(36, CC), 256, 0, stream>>>(att, Ww, Wb, xg, out);
}

// Round 14
// 105.381 us; speedup vs baseline: 1.1083x; 1.0204x over previous
//
#include <hip/hip_runtime.h>
#include <math.h>

#define NTOK 9216      // 96*96 tokens
#define CIN  32        // inner channels
#define CC   64        // outer channels
#define NCH1 24        // phase1 n-chunks
#define NT1S 24        // n-tile steps per phase1 chunk: 576/24
#define NCH2 16        // phase2 m-chunks
#define MS2  18        // m-steps (32-wide) per phase2 chunk: 9216/16/32
#define MCH2 576       // m per phase2 chunk
#define LOG2E 1.4426950408889634f
#define C1INIT (-17.312340490667560f)   // -12*log2e
#define C2INIT (-9.3123404906675595f)   // -12*log2e + 8  (+8 = *256 f16-underflow guard)

typedef _Float16 half8 __attribute__((ext_vector_type(8)));
typedef _Float16 half4v __attribute__((ext_vector_type(4)));
typedef __fp16   fp16x2 __attribute__((ext_vector_type(2)));   // cvt_pkrtz return type
typedef float    f32x4 __attribute__((ext_vector_type(4)));

static __device__ __forceinline__ float fexp2(float x) {
#if __has_builtin(__builtin_amdgcn_exp2f)
    return __builtin_amdgcn_exp2f(x);
#else
    return exp2f(x);
#endif
}

// ---------------- conv1: 3x3 s2 p1, LDS-staged, full-oc per block, CIG=4 ----------------
// grid (48, 16): x = output row oh, y = 4-ci group. block 192.
__global__ __launch_bounds__(192) void conv3x3_lds96(const float* __restrict__ in,
                                                     const float* __restrict__ w,
                                                     float* __restrict__ outp) {
    __shared__ float li[4][3][100];   // [ci][kh][col] ; col = iw+1 (0..96)
    __shared__ float lw[4][9][64];    // [ci][k][oc]
    const int t = threadIdx.x;
    const int oh = blockIdx.x, grp = blockIdx.y;
    const int ci0 = grp * 4;
    for (int idx = t; idx < 4 * 3 * 97; idx += 192) {
        int ci = idx / 291, rem = idx % 291;
        int kh = rem / 97, col = rem % 97;
        int ih = 2 * oh - 1 + kh, iw = col - 1;
        float v = 0.f;
        if (ih >= 0 && iw >= 0) v = in[(ci0 + ci) * 9216 + ih * 96 + iw];
        li[ci][kh][col] = v;
    }
    for (int idx = t; idx < 4 * 9 * 64; idx += 192) {
        int oc = idx / 36, r = idx % 36;
        int ci = r / 9, k = r % 9;
        lw[ci][k][oc] = w[oc * 576 + (ci0 + ci) * 9 + k];
    }
    __syncthreads();
    const int oc0 = (t & 15) * 4;
    const int ow0 = (t >> 4) * 4;
    float acc[4][4] = {};   // [px][oc]
    #pragma unroll
    for (int ci = 0; ci < 4; ++ci) {
        float wr[9][4];
        #pragma unroll
        for (int k = 0; k < 9; ++k)
            *(float4*)wr[k] = *(const float4*)&lw[ci][k][oc0];
        #pragma unroll
        for (int kh = 0; kh < 3; ++kh) {
            float v[9];
            #pragma unroll
            for (int j = 0; j < 9; ++j) v[j] = li[ci][kh][2 * ow0 + j];
            #pragma unroll
            for (int px = 0; px < 4; ++px)
                #pragma unroll
                for (int kw = 0; kw < 3; ++kw) {
                    float xv = v[2 * px + kw];
                    #pragma unroll
                    for (int o = 0; o < 4; ++o)
                        acc[px][o] = fmaf(xv, wr[kh * 3 + kw][o], acc[px][o]);
                }
        }
    }
    float* op = outp + grp * (CC * 2304) + oh * 48 + ow0;
    #pragma unroll
    for (int o = 0; o < 4; ++o)
        *(float4*)(op + (oc0 + o) * 2304) =
            make_float4(acc[0][o], acc[1][o], acc[2][o], acc[3][o]);
}

// ---------------- generic small conv 3x3 s2 p1: partial over ci-groups ----------------
template<int HIN, int HOUT, int CIG>
__global__ void conv3x3_part(const float* __restrict__ in, const float* __restrict__ w,
                             float* __restrict__ outp) {
    const int p = blockIdx.x * blockDim.x + threadIdx.x;
    if (p >= HOUT * HOUT) return;
    const int oc = blockIdx.y, grp = blockIdx.z;
    const int oh = p / HOUT, ow = p % HOUT;
    const int ci0 = grp * CIG;
    float acc = 0.f;
    #pragma unroll
    for (int ci = 0; ci < CIG; ++ci) {
        const float* ip = in + (ci0 + ci) * HIN * HIN;
        const float* wp = w + oc * CC * 9 + (ci0 + ci) * 9;
        #pragma unroll
        for (int kh = 0; kh < 3; ++kh) {
            int ih = oh * 2 - 1 + kh;
            bool okh = (unsigned)ih < (unsigned)HIN;
            #pragma unroll
            for (int kw = 0; kw < 3; ++kw) {
                int iw = ow * 2 - 1 + kw;
                float v = (okh && (unsigned)iw < (unsigned)HIN) ? ip[ih * HIN + iw] : 0.f;
                acc = fmaf(v, wp[kh * 3 + kw], acc);
            }
        }
    }
    outp[grp * (CC * HOUT * HOUT) + oc * HOUT * HOUT + p] = acc;
}

// ---------------- merge conv partials + bias + (leaky)relu, float4 ----------------
template<int NG, int HW, int LRELU>
__global__ void conv_merge4(const float* __restrict__ parts, const float* __restrict__ b,
                            float* __restrict__ out) {
    int i4 = blockIdx.x * 256 + threadIdx.x;    // CC*HW/4 total
    int oc = (i4 * 4) / HW;
    float bb = b[oc];
    float4 acc = make_float4(bb, bb, bb, bb);
    #pragma unroll
    for (int g = 0; g < NG; ++g) {
        float4 p = *(const float4*)(parts + g * (CC * HW) + i4 * 4);
        acc.x += p.x; acc.y += p.y; acc.z += p.z; acc.w += p.w;
    }
    if (LRELU) {
        acc.x = acc.x >= 0.f ? acc.x : 0.2f * acc.x;
        acc.y = acc.y >= 0.f ? acc.y : 0.2f * acc.y;
        acc.z = acc.z >= 0.f ? acc.z : 0.2f * acc.z;
        acc.w = acc.w >= 0.f ? acc.w : 0.2f * acc.w;
    }
    *(float4*)(out + i4 * 4) = acc;
}

// ---------------- gate helper: bilinear 12->96 + sigmoid ----------------
static __device__ __forceinline__ float gate_val(const float* y3c, int n) {
    int h = n / 96, wc = n % 96;
    float fh = (h + 0.5f) * 0.125f - 0.5f;
    float fw = (wc + 0.5f) * 0.125f - 0.5f;
    int h0 = (int)floorf(fh); float ah = fh - (float)h0;
    int w0 = (int)floorf(fw); float aw = fw - (float)w0;
    int h0c = min(max(h0, 0), 11), h1c = min(max(h0 + 1, 0), 11);
    int w0c = min(max(w0, 0), 11), w1c = min(max(w0 + 1, 0), 11);
    float v = (1.f - ah) * ((1.f - aw) * y3c[h0c * 12 + w0c] + aw * y3c[h0c * 12 + w1c])
            +         ah * ((1.f - aw) * y3c[h1c * 12 + w0c] + aw * y3c[h1c * 12 + w1c]);
    return 1.f / (1.f + __expf(-v));
}

// ---------------- fused: merge conv3 partials + gate -> xg ----------------
__global__ void gate_fused(const float* __restrict__ x, const float* __restrict__ cp3,
                           const float* __restrict__ d3b, float* __restrict__ xg) {
    __shared__ float y3c[144];
    const int b = blockIdx.x, t = threadIdx.x;
    const int c = b / 36;
    if (t < 144) {
        float acc = d3b[c];
        #pragma unroll
        for (int g = 0; g < 16; ++g)
            acc += cp3[g * (CC * 144) + c * 144 + t];
        y3c[t] = acc;
    }
    __syncthreads();
    int idx = b * 256 + t;
    int n = idx % 9216;
    float sg = gate_val(y3c, n);
    xg[idx] = sg * x[idx];
}

// ---------------- 1x1 convs -> f16 fragments written DIRECTLY ----------------
__global__ void conv1x1_frag(const float* __restrict__ xg,
                             const float* __restrict__ gw, const float* __restrict__ gb,
                             const float* __restrict__ thw, const float* __restrict__ thb,
                             const float* __restrict__ phw, const float* __restrict__ phb,
                             _Float16* __restrict__ txF, _Float16* __restrict__ pxF,
                             _Float16* __restrict__ gxF) {
    int ci = blockIdx.y;
    int n = blockIdx.x * 256 + threadIdx.x;
    float ag = gb[ci], at = thb[ci], ap = phb[ci];
    #pragma unroll 8
    for (int c = 0; c < CC; ++c) {
        float v = xg[c * NTOK + n];
        ag = fmaf(gw[ci * CC + c],  v, ag);
        at = fmaf(thw[ci * CC + c], v, at);
        ap = fmaf(phw[ci * CC + c], v, ap);
    }
    int addr_ab = (n >> 4) * 512 + (((n & 15) | (((ci & 15) >> 2) << 4)) * 8)
                + (((ci >> 4) << 2) | (ci & 3));
    txF[addr_ab] = (_Float16)(at * LOG2E);
    pxF[addr_ab] = (_Float16)ap;
    int addr_g = ((n >> 5) * 2 + (ci >> 4)) * 512
               + (((ci & 15) | (((n & 15) >> 2) << 4)) * 8)
               + ((((n >> 4) & 1) << 2) | (n & 3));
    gxF[addr_g] = (_Float16)ag;
}

// ---------------- phase 1: Dp[m] = sum_n exp2(s'), 4 m-tiles per wave ----------------
__global__ __launch_bounds__(256) void phase1(const _Float16* __restrict__ txF,
                                              const _Float16* __restrict__ pxF,
                                              float* __restrict__ Dp) {
    int w = threadIdx.x >> 6, l = threadIdx.x & 63;
    int mtile0 = (blockIdx.x * 4 + w) * 4;
    half8 pf[4];
    #pragma unroll
    for (int j = 0; j < 4; ++j)
        pf[j] = *(const half8*)(pxF + (mtile0 + j) * 512 + l * 8);
    f32x4 cini = {C1INIT, C1INIT, C1INIT, C1INIT};
    float dsum[4][4] = {};
    int nt0 = blockIdx.y * NT1S;
    #pragma unroll 2
    for (int i = 0; i < NT1S; ++i) {
        half8 tf = *(const half8*)(txF + (nt0 + i) * 512 + l * 8);
        #pragma unroll
        for (int j = 0; j < 4; ++j) {
            f32x4 s = __builtin_amdgcn_mfma_f32_16x16x32_f16(pf[j], tf, cini, 0, 0, 0);
            #pragma unroll
            for (int r = 0; r < 4; ++r)
                dsum[j][r] += fexp2(s[r]);
        }
    }
    #pragma unroll
    for (int off = 1; off < 16; off <<= 1)
        #pragma unroll
        for (int j = 0; j < 4; ++j)
            #pragma unroll
            for (int r = 0; r < 4; ++r)
                dsum[j][r] += __shfl_xor(dsum[j][r], off);
    if ((l & 15) == 0) {
        #pragma unroll
        for (int j = 0; j < 4; ++j) {
            int m = (mtile0 + j) * 16 + (l >> 4) * 4;
            #pragma unroll
            for (int r = 0; r < 4; ++r)
                Dp[blockIdx.y * NTOK + m + r] = dsum[j][r];
        }
    }
}

// ---------------- phase 2: y2 = sum_m 2^(s'-log2D)*g; Dp merged in prologue; f16 out ----------------
__global__ __launch_bounds__(256) void phase2(const _Float16* __restrict__ txF,
                                              const _Float16* __restrict__ pxF,
                                              const _Float16* __restrict__ gxF,
                                              const float* __restrict__ Dp,
                                              _Float16* __restrict__ y2p) {
    __shared__ float l2D[MCH2];
    int mbase = blockIdx.y * MCH2;
    for (int i = threadIdx.x; i < MCH2; i += 256) {
        float D = 0.f;
        #pragma unroll
        for (int ch = 0; ch < NCH1; ++ch) D += Dp[ch * NTOK + mbase + i];
        l2D[i] = __log2f(D);
    }
    __syncthreads();
    int w = threadIdx.x >> 6, l = threadIdx.x & 63;
    int ntile0 = (blockIdx.x * 4 + w) * 4;
    half8 tf[4];
    #pragma unroll
    for (int j = 0; j < 4; ++j)
        tf[j] = *(const half8*)(txF + (ntile0 + j) * 512 + l * 8);
    int khi = (l >> 4) * 4;
    f32x4 zero = {0.f, 0.f, 0.f, 0.f};
    f32x4 c2v = {C2INIT, C2INIT, C2INIT, C2INIT};
    f32x4 acc[4][2];
    #pragma unroll
    for (int j = 0; j < 4; ++j) { acc[j][0] = zero; acc[j][1] = zero; }
    #pragma unroll 2
    for (int ms = 0; ms < MS2; ++ms) {
        int m0 = mbase + ms * 32;
        int mloc = ms * 32;
        int mt16 = m0 >> 4;
        half8 pf0 = *(const half8*)(pxF + mt16 * 512 + l * 8);
        half8 pf1 = *(const half8*)(pxF + (mt16 + 1) * 512 + l * 8);
        f32x4 l2a = *(const f32x4*)&l2D[mloc + khi];
        f32x4 l2b = *(const f32x4*)&l2D[mloc + 16 + khi];
        f32x4 cini0 = c2v - l2a;
        f32x4 cini1 = c2v - l2b;
        int gt = (m0 >> 5) * 2;
        half8 gf0 = *(const half8*)(gxF + gt * 512 + l * 8);
        half8 gf1 = *(const half8*)(gxF + (gt + 1) * 512 + l * 8);
        #pragma unroll
        for (int j = 0; j < 4; ++j) {
            f32x4 s0 = __builtin_amdgcn_mfma_f32_16x16x32_f16(pf0, tf[j], cini0, 0, 0, 0);
            f32x4 s1 = __builtin_amdgcn_mfma_f32_16x16x32_f16(pf1, tf[j], cini1, 0, 0, 0);
            // packed f32->f16 conversion (cvt_pkrtz): 4 ops instead of 8 scalar cvts
            union { half8 v; fp16x2 h2[4]; } U;
            U.h2[0] = __builtin_amdgcn_cvt_pkrtz(fexp2(s0[0]), fexp2(s0[1]));
            U.h2[1] = __builtin_amdgcn_cvt_pkrtz(fexp2(s0[2]), fexp2(s0[3]));
            U.h2[2] = __builtin_amdgcn_cvt_pkrtz(fexp2(s1[0]), fexp2(s1[1]));
            U.h2[3] = __builtin_amdgcn_cvt_pkrtz(fexp2(s1[2]), fexp2(s1[3]));
            acc[j][0] = __builtin_amdgcn_mfma_f32_16x16x32_f16(U.v, gf0, acc[j][0], 0, 0, 0);
            acc[j][1] = __builtin_amdgcn_mfma_f32_16x16x32_f16(U.v, gf1, acc[j][1], 0, 0, 0);
        }
    }
    _Float16* base = y2p + blockIdx.y * (CIN * NTOK);
    #pragma unroll
    for (int j = 0; j < 4; ++j) {
        int n = (ntile0 + j) * 16 + khi;
        half4v v0, v1;
        #pragma unroll
        for (int r = 0; r < 4; ++r) {
            v0[r] = (_Float16)(acc[j][0][r] * 0.00390625f);
            v1[r] = (_Float16)(acc[j][1][r] * 0.00390625f);
        }
        *(half4v*)(base + (l & 15) * NTOK + n)        = v0;
        *(half4v*)(base + (16 + (l & 15)) * NTOK + n) = v1;
    }
}

// ---------------- merge y2 partials (f16 in, f32 out) ----------------
__global__ void mergeY2(const _Float16* __restrict__ y2p, float* __restrict__ att) {
    int i4 = blockIdx.x * 256 + threadIdx.x;   // 32*9216/4 = 73728 -> 288 blocks
    float4 s = make_float4(0.f, 0.f, 0.f, 0.f);
    #pragma unroll
    for (int ch = 0; ch < NCH2; ++ch) {
        half4v p = *(const half4v*)(y2p + ch * (CIN * NTOK) + i4 * 4);
        s.x += (float)p[0]; s.y += (float)p[1]; s.z += (float)p[2]; s.w += (float)p[3];
    }
    *(float4*)(att + i4 * 4) = s;
}

// ---------------- final 1x1 conv + residual ----------------
__global__ void final_conv(const float* __restrict__ att, const float* __restrict__ Ww,
                           const float* __restrict__ Wb, const float* __restrict__ xg,
                           float* __restrict__ out) {
    int co = blockIdx.y;
    int n = blockIdx.x * 256 + threadIdx.x;
    float acc = Wb[co];
    #pragma unroll
    for (int ci = 0; ci < CIN; ++ci)
        acc = fmaf(Ww[co * CIN + ci], att[ci * NTOK + n], acc);
    out[co * NTOK + n] = acc + xg[co * NTOK + n];
}

extern "C" void kernel_launch(void* const* d_in, const int* in_sizes, int n_in,
                              void* d_out, int out_size, void* d_ws, size_t ws_size,
                              hipStream_t stream) {
    const float* x   = (const float*)d_in[0];
    const float* d1w = (const float*)d_in[1];  const float* d1b = (const float*)d_in[2];
    const float* d2w = (const float*)d_in[3];  const float* d2b = (const float*)d_in[4];
    const float* d3w = (const float*)d_in[5];  const float* d3b = (const float*)d_in[6];
    const float* gw  = (const float*)d_in[7];  const float* gb  = (const float*)d_in[8];
    const float* thw = (const float*)d_in[9];  const float* thb = (const float*)d_in[10];
    const float* phw = (const float*)d_in[11]; const float* phb = (const float*)d_in[12];
    const float* Ww  = (const float*)d_in[13]; const float* Wb  = (const float*)d_in[14];
    float* out = (float*)d_out;

    float* W    = (float*)d_ws;
    float* xg   = W;                  // 589824
    float* y1   = W + 589824;         // -> 737280
    float* y2c  = W + 737280;         // -> 774144
    float* Dp   = W + 774144;         // 24*9216 -> 995328
    float* att  = W + 995328;         // -> 1290240
    float* cp1  = W + 1290240;        // 16*147456 = 2359296 -> 3649536
    float* cp2  = W + 3649536;        // 16*36864  = 589824  -> 4239360
    float* cp3  = W + 4239360;        // 16*9216   = 147456  -> 4386816
    _Float16* txF  = (_Float16*)(W + 4386816);  // 294912 f16 -> +147456 fl
    _Float16* pxF  = (_Float16*)(W + 4534272);
    _Float16* gxF  = (_Float16*)(W + 4681728);  // -> 4829184
    _Float16* y2pH = (_Float16*)(W + 4829184);  // 16*294912 f16 = 1179648 fl -> 6008832 (24 MB)

    // gating branch (reads ORIGINAL x)
    conv3x3_lds96<<<dim3(48, 16), 192, 0, stream>>>(x, d1w, cp1);
    conv_merge4<16, 2304, 1><<<144, 256, 0, stream>>>(cp1, d1b, y1);
    conv3x3_part<48, 24, 4><<<dim3(3, CC, 16), 192, 0, stream>>>(y1, d2w, cp2);
    conv_merge4<16, 576, 1><<<36, 256, 0, stream>>>(cp2, d2b, y2c);
    conv3x3_part<24, 12, 4><<<dim3(1, CC, 16), 192, 0, stream>>>(y2c, d3w, cp3);
    gate_fused<<<2304, 256, 0, stream>>>(x, cp3, d3b, xg);

    // 1x1 projections -> f16 fragments direct
    conv1x1_frag<<<dim3(36, CIN), 256, 0, stream>>>(xg, gw, gb, thw, thb, phw, phb,
                                                    txF, pxF, gxF);

    // attention via MFMA
    phase1<<<dim3(36, NCH1), 256, 0, stream>>>(txF, pxF, Dp);
    phase2<<<dim3(36, NCH2), 256, 0, stream>>>(txF, pxF, gxF, Dp, y2pH);
    mergeY2<<<288, 256, 0, stream>>>(y2pH, att);

    // output
    final_conv<<<dim3(36, CC), 256, 0, stream>>>(att, Ww, Wb, xg, out);
}